// Round 16
// baseline (108.959 us; speedup 1.0000x reference)
//
#include <hip/hip_runtime.h>

// VQC, 8 qubits, 256 real fp32 amplitudes. One sample per QUAD (4 lanes).
// Amplitude index j (8 bits): j[5:0] = register index (qubits 0..5),
// j[6] = lane bit0 (qubit 6), j[7] = lane bit1 (qubit 7).
// Cross-lane = quad_perm DPP (VALU pipe, no DS usage).
// Variational RY uses tan-form: RY = cos * [[1,-t],[t,1]]; the cos factors are
// lane-uniform (shared weights) and fold into one final scale C2 = (prod cos)^2.
// Scalar fmaf only — NO inline asm, NO ext_vector arrays: round 13 showed the
// f32x2 asm operand pairs fragment regalloc into a 100 MB/dispatch scratch
// spill (FETCH 31.8 MB / WRITE 75.8 MB vs 4/4 MB ideal). launch_bounds(256,2)
// lifts the unified-reg cap to 256 so the ~110-reg live state never spills.

#define DPP_XOR1   0xB1  // quad_perm [1,0,3,2]
#define DPP_XOR2   0x4E  // quad_perm [2,3,0,1]
#define DPP_CNOT67 0x6C  // quad_perm [0,3,2,1]: lanes with bit0=1 swap across bit1

template<int CTRL>
__device__ __forceinline__ float dppf(float v) {
    return __int_as_float(__builtin_amdgcn_mov_dpp(__float_as_int(v), CTRL, 0xF, 0xF, true));
}

// sin/cos of theta/2 via hw v_sin/v_cos (revolutions); |theta|<=~5.3 in range
__device__ __forceinline__ void sc_half(float theta, float* s, float* c) {
    const float rev = theta * 0.07957747154594767f;  // (theta/2) / (2*pi)
    *s = __builtin_amdgcn_sinf(rev);
    *c = __builtin_amdgcn_cosf(rev);
}

__global__ void __launch_bounds__(256, 2) vqc_kernel(const float* __restrict__ x,
                                                     const float* __restrict__ w,
                                                     float* __restrict__ out, int B)
{
    const int tid = blockIdx.x * blockDim.x + threadIdx.x;
    const int k   = tid & 3;        // lane-in-quad: bit0 -> q6, bit1 -> q7
    const int s   = tid >> 2;       // sample index
    if (s >= B) return;

    // ---- encode: H+RY(x) on |0> is a product state: u(0)=(c-s), u(1)=(c+s), /sqrt2 each
    const float4 x0 = *(const float4*)(x + s * 8);
    const float4 x1 = *(const float4*)(x + s * 8 + 4);
    const float ang[8] = {x0.x, x0.y, x0.z, x0.w, x1.x, x1.y, x1.z, x1.w};
    float u0[8], u1[8];
    #pragma unroll
    for (int q = 0; q < 8; ++q) {
        float sv, cv; sc_half(ang[q], &sv, &cv);
        u0[q] = cv - sv; u1[q] = cv + sv;
    }
    const float fl = 0.0625f * ((k & 1) ? u1[6] : u0[6]) * ((k & 2) ? u1[7] : u0[7]);

    // product tree over register qubits 0..5 -> a[64]
    float a[64];
    a[0] = fl * u0[0];
    a[1] = fl * u1[0];
    #pragma unroll
    for (int q = 1; q < 6; ++q) {
        const int h = 1 << q;
        #pragma unroll
        for (int r = h - 1; r >= 0; --r) {
            const float base = a[r];
            a[r + h] = base * u1[q];
            a[r]     = base * u0[q];
        }
    }

    // ---- per-gate tangents for the 32 variational RYs (lane-uniform weights)
    float tl[32];
    float prodc = 1.0f;
    #pragma unroll
    for (int g = 0; g < 32; ++g) {
        float sv, cv; sc_half(w[g], &sv, &cv);
        tl[g] = __fdividef(sv, cv);
        prodc *= cv;
    }
    const float C2 = prodc * prodc;   // fold all cos factors into final <Z>

    // ---- 4 variational layers
    #pragma unroll
    for (int layer = 0; layer < 4; ++layer) {
        const float* tw = tl + layer * 8;

        // CNOT(0,1): ctrl reg bit0, tgt reg bit1 -> register rename (free)
        #pragma unroll
        for (int r = 0; r < 64; ++r)
            if ((r & 1) && !(r & 2)) { float t = a[r]; a[r] = a[r | 2]; a[r | 2] = t; }
        // CNOT(2,3)
        #pragma unroll
        for (int r = 0; r < 64; ++r)
            if ((r & 4) && !(r & 8)) { float t = a[r]; a[r] = a[r | 8]; a[r | 8] = t; }
        // CNOT(4,5)
        #pragma unroll
        for (int r = 0; r < 64; ++r)
            if ((r & 16) && !(r & 32)) { float t = a[r]; a[r] = a[r | 32]; a[r | 32] = t; }
        // CNOT(6,7): ctrl lane bit0, tgt lane bit1 -> one quad_perm, no select
        #pragma unroll
        for (int r = 0; r < 64; ++r) a[r] = dppf<DPP_CNOT67>(a[r]);
        // CNOT(1,2)
        #pragma unroll
        for (int r = 0; r < 64; ++r)
            if ((r & 2) && !(r & 4)) { float t = a[r]; a[r] = a[r | 4]; a[r | 4] = t; }
        // CNOT(3,4)
        #pragma unroll
        for (int r = 0; r < 64; ++r)
            if ((r & 8) && !(r & 16)) { float t = a[r]; a[r] = a[r | 16]; a[r | 16] = t; }
        // CNOT(5,6): ctrl reg bit5, tgt lane bit0 -> quad_perm xor1 on regs 32..63
        #pragma unroll
        for (int r = 32; r < 64; ++r) a[r] = dppf<DPP_XOR1>(a[r]);

        // RY q0..q5, tan form: lo' = lo - t*hi ; hi' = hi + t*lo
        #pragma unroll
        for (int q = 0; q < 6; ++q) {
            const float t = tw[q];
            const int m = 1 << q;
            #pragma unroll
            for (int r = 0; r < 64; ++r) {
                if (!(r & m)) {
                    const float lo = a[r], hi = a[r | m];
                    a[r]     = fmaf(-t, hi, lo);
                    a[r | m] = fmaf( t, lo, hi);
                }
            }
        }
        // RY q6: partner across lane bit0; a' = a + (bit? t : -t)*partner
        {
            const float st = (k & 1) ? tw[6] : -tw[6];
            #pragma unroll
            for (int r = 0; r < 64; ++r)
                a[r] = fmaf(st, dppf<DPP_XOR1>(a[r]), a[r]);
        }
        // RY q7: partner across lane bit1
        {
            const float st = (k & 2) ? tw[7] : -tw[7];
            #pragma unroll
            for (int r = 0; r < 64; ++r)
                a[r] = fmaf(st, dppf<DPP_XOR2>(a[r]), a[r]);
        }
    }

    // ---- measurement: <Z_i> = C2 * sum_j (-1)^{bit_i(j)} amp_j^2
    // square in place, then a halving even/odd tree with no temp arrays
    #pragma unroll
    for (int r = 0; r < 64; ++r) a[r] = a[r] * a[r];

    float z[8];
    #pragma unroll
    for (int q = 0; q < 6; ++q) {
        const int n = 64 >> q;          // live prefix length of a[]
        float zz = 0.0f;
        #pragma unroll
        for (int i = 0; i < n / 2; ++i) {
            const float e = a[2 * i], o = a[2 * i + 1];
            zz  += e - o;
            a[i] = e + o;
        }
        z[q] = zz;
    }
    const float t = a[0];               // per-lane total probability

    // quad reductions (DPP): z0..z5 sum over 4 lanes
    #pragma unroll
    for (int q = 0; q < 6; ++q) {
        z[q] += dppf<DPP_XOR1>(z[q]);
        z[q] += dppf<DPP_XOR2>(z[q]);
    }
    // z6 = P(q6=0)-P(q6=1), z7 = P(q7=0)-P(q7=1)
    {
        const float v  = dppf<DPP_XOR1>(t);
        const float d6 = (k & 1) ? (v - t) : (t - v);
        z[6] = d6 + dppf<DPP_XOR2>(d6);
        const float wv = dppf<DPP_XOR2>(t);
        const float d7 = (k & 2) ? (wv - t) : (t - wv);
        z[7] = d7 + dppf<DPP_XOR1>(d7);
    }
    #pragma unroll
    for (int j = 0; j < 8; ++j) z[j] *= C2;

    // store: lane k of the quad writes out[8s+2k], out[8s+2k+1] (8B/lane, coalesced)
    const float lo = (k == 0) ? z[0] : (k == 1) ? z[2] : (k == 2) ? z[4] : z[6];
    const float hi = (k == 0) ? z[1] : (k == 1) ? z[3] : (k == 2) ? z[5] : z[7];
    *(float2*)(out + s * 8 + k * 2) = make_float2(lo, hi);
}

extern "C" void kernel_launch(void* const* d_in, const int* in_sizes, int n_in,
                              void* d_out, int out_size, void* d_ws, size_t ws_size,
                              hipStream_t stream) {
    const float* x = (const float*)d_in[0];
    const float* w = (const float*)d_in[1];
    float* out = (float*)d_out;
    const int B = in_sizes[0] / 8;                  // 131072 samples
    const int total_threads = B * 4;                // 4 lanes per sample
    const int blocks = (total_threads + 255) / 256;
    hipLaunchKernelGGL(vqc_kernel, dim3(blocks), dim3(256), 0, stream, x, w, out, B);
}